// Round 15
// baseline (404.845 us; speedup 1.0000x reference)
//
#include <hip/hip_runtime.h>
#include <hip/hip_bf16.h>

#define TT 4
#define HH 4
#define DD 128
#define KAGG 2048   // TT * HH * DD

typedef __attribute__((ext_vector_type(8))) short short8;
typedef __attribute__((ext_vector_type(4))) float f32x4;
typedef __attribute__((ext_vector_type(4))) unsigned int uint4v;

__device__ __forceinline__ float lrelu(float z) { return z > 0.f ? z : 0.2f * z; }
__device__ __forceinline__ float bf2f(unsigned short u) {
  union { unsigned int i; float f; } v; v.i = ((unsigned int)u) << 16; return v.f;
}
__device__ __forceinline__ unsigned short f2b(float f) {
  union { float f; unsigned int i; } u; u.f = f;
  unsigned int r = u.i + 0x7fff + ((u.i >> 16) & 1);
  return (unsigned short)(r >> 16);
}
__device__ __forceinline__ void unpack8v(uint4v u, float* hv) {
  hv[0] = bf2f((unsigned short)(u.x & 0xffff));
  hv[1] = bf2f((unsigned short)(u.x >> 16));
  hv[2] = bf2f((unsigned short)(u.y & 0xffff));
  hv[3] = bf2f((unsigned short)(u.y >> 16));
  hv[4] = bf2f((unsigned short)(u.z & 0xffff));
  hv[5] = bf2f((unsigned short)(u.z >> 16));
  hv[6] = bf2f((unsigned short)(u.w & 0xffff));
  hv[7] = bf2f((unsigned short)(u.w >> 16));
}

// ======== prologue: convx | Pall | cbias | hist
__global__ __launch_bounds__(256) void prologue_kernel(
    const float* __restrict__ x, unsigned short* __restrict__ xb, int total4,
    const float* __restrict__ Wg, const float* __restrict__ a_s,
    const float* __restrict__ a_d, const float* __restrict__ W_fuse,
    const float* __restrict__ b_gat, const float* __restrict__ etw,
    const float* __restrict__ b_fuse, unsigned short* __restrict__ Pall,
    float* __restrict__ cbias, const int* __restrict__ dst,
    const int* __restrict__ attr, int* __restrict__ deg, int E, int N) {
  int bid = blockIdx.x;
  const int nconv = (total4 + 255) >> 8;
  if (bid < nconv) {                       // ---- convx
    int i = bid * 256 + threadIdx.x;
    if (i < total4) {
      float4 v = ((const float4*)x)[i];
      ushort4 o;
      o.x = f2b(v.x); o.y = f2b(v.y); o.z = f2b(v.z); o.w = f2b(v.w);
      ((ushort4*)xb)[i] = o;
    }
    return;
  }
  bid -= nconv;
  if (bid < 17) {
    float e0 = etw[0], e1 = etw[1], e2 = etw[2], e3 = etw[3];
    float mx = fmaxf(fmaxf(e0, e1), fmaxf(e2, e3));
    float w0 = __expf(e0 - mx), w1 = __expf(e1 - mx), w2 = __expf(e2 - mx),
          w3 = __expf(e3 - mx);
    float inv = 1.f / (w0 + w1 + w2 + w3);
    float wts[4] = {w0 * inv, w1 * inv, w2 * inv, w3 * inv};
    if (bid < 16) {                        // ---- Pall: 32*128
      int idx = bid * 256 + threadIdx.x;
      int c = idx >> 7, k = idx & 127;
      int t = c >> 3, jj = c & 7, head = jj & 3;
      const float* av = ((jj < 4) ? a_s : a_d) + (t * 4 + head) * 128;
      const float* wr = Wg + (size_t)t * 65536 + k * 512 + head * 128;
      float s = 0.f;
      for (int m = 0; m < 128; ++m) s += wr[m] * av[m];
      Pall[c * 128 + k] = f2b(s);
    } else {                               // ---- cbias
      int j = threadIdx.x;
      if (j < 128) {
        float s = b_fuse[j];
        for (int t = 0; t < 4; ++t) {
          float st = 0.f;
          for (int m = 0; m < 128; ++m)
            st += b_gat[t * 128 + m] * W_fuse[(size_t)(t * 128 + m) * 128 + j];
          s += wts[t] * st;
        }
        cbias[j] = s;
      }
    }
    return;
  }
  bid -= 17;                               // ---- hist
  int e = bid * 256 + threadIdx.x;
  if (e < E) atomicAdd(&deg[attr[e] * N + dst[e]], 1);
}

// ======== stage2: scan | gprep | alpha
__global__ __launch_bounds__(256) void stage2_kernel(
    const int* __restrict__ deg, int* __restrict__ rowptr,
    int* __restrict__ cursor, int* __restrict__ gcur, int M,
    const float* __restrict__ Wg, const float* __restrict__ W_fuse,
    const float* __restrict__ etw, unsigned short* __restrict__ Gfrag,
    const unsigned short* __restrict__ xb, const unsigned short* __restrict__ Pall,
    float* __restrict__ as_, float* __restrict__ ad_, int N) {
  __shared__ __align__(16) unsigned char smem[65536 + 16];
  int bid = blockIdx.x;
  const int nscan = (M + 255) >> 8;
  if (bid < nscan) {                       // ---- scan (256-chunk, atomic base)
    int* sh = (int*)smem;
    int* basep = (int*)(smem + 65536);
    int i = bid * 256 + threadIdx.x;
    int v = (i < M) ? deg[i] : 0;
    sh[threadIdx.x] = v;
    __syncthreads();
    for (int off = 1; off < 256; off <<= 1) {
      int xx = (threadIdx.x >= off) ? sh[threadIdx.x - off] : 0;
      __syncthreads();
      sh[threadIdx.x] += xx;
      __syncthreads();
    }
    if (threadIdx.x == 255) *basep = atomicAdd(gcur, sh[255]);
    __syncthreads();
    if (i < M) {
      int r = *basep + sh[threadIdx.x] - v;
      rowptr[i] = r;
      cursor[i] = r;
    }
    return;
  }
  bid -= nscan;
  if (bid < 256) {                         // ---- gprep (LDS-cached W_fuse_t)
    float(*Bs)[128] = (float(*)[128])smem;  // 64KB
    int t = bid >> 6;
    int kr0 = (bid & 63) * 8;
    const float* wf = W_fuse + (size_t)t * 16384;
#pragma unroll
    for (int i = 0; i < 64; ++i)
      ((float*)Bs)[i * 256 + threadIdx.x] = wf[i * 256 + threadIdx.x];

    float e0 = etw[0], e1 = etw[1], e2 = etw[2], e3 = etw[3];
    float mx = fmaxf(fmaxf(e0, e1), fmaxf(e2, e3));
    float w0 = __expf(e0 - mx), w1 = __expf(e1 - mx), w2 = __expf(e2 - mx),
          w3 = __expf(e3 - mx);
    float inv = 1.f / (w0 + w1 + w2 + w3);
    float wt = ((t == 0) ? w0 : (t == 1) ? w1 : (t == 2) ? w2 : w3) * inv * 0.25f;
    __syncthreads();

    int rr = threadIdx.x >> 7;
    int j = threadIdx.x & 127;
#pragma unroll
    for (int r2 = 0; r2 < 4; ++r2) {
      int kr = kr0 + r2 * 2 + rr;
      int head = kr >> 7, k = kr & 127;
      const float* wr = Wg + (size_t)t * 65536 + k * 512 + head * 128;
      float s = 0.f;
      for (int m = 0; m < 128; ++m) s += wr[m] * Bs[m][j];
      s *= wt;
      int K = t * 512 + kr;
      int kt = K >> 7, kk = (K >> 5) & 3, n = j >> 4;
      int f = (kt * 4 + kk) * 8 + n;
      int lg = (K >> 3) & 3, lr = j & 15, j8 = K & 7;
      Gfrag[(size_t)f * 512 + (lg * 16 + lr) * 8 + j8] = f2b(s);
    }
    return;
  }
  bid -= 256;                              // ---- alpha via MFMA
  unsigned char* lds = smem;               // 32KB used
  const int n0 = bid * 128;
  const int tid = threadIdx.x, lane = tid & 63, wid = tid >> 6;
  const int lr = lane & 15, lg = lane >> 4;
#pragma unroll
  for (int i = 0; i < 8; ++i) {
    int chunk = tid + i * 256;
    int row = chunk >> 4, k16 = chunk & 15;
    int gr = n0 + row;
    uint4 v = make_uint4(0, 0, 0, 0);
    if (gr < N) v = *(const uint4*)(xb + (size_t)gr * DD + k16 * 8);
    *(uint4*)(lds + ((row * 256 + k16 * 16) ^ ((row & 7) << 4))) = v;
  }
  __syncthreads();
  f32x4 acc[2][2] = {};
#pragma unroll
  for (int kk = 0; kk < 4; ++kk) {
    short8 a[2], b[2];
#pragma unroll
    for (int m = 0; m < 2; ++m) {
      int row = wid * 32 + m * 16 + lr;
      a[m] = *(const short8*)(lds + ((row * 256 + kk * 64 + (lg << 4)) ^ ((row & 7) << 4)));
    }
#pragma unroll
    for (int n = 0; n < 2; ++n) {
      int c = n * 16 + lr;
      b[n] = *(const short8*)(Pall + c * DD + kk * 32 + lg * 8);
    }
#pragma unroll
    for (int m = 0; m < 2; ++m)
#pragma unroll
      for (int n = 0; n < 2; ++n)
        acc[m][n] = __builtin_amdgcn_mfma_f32_16x16x32_bf16(a[m], b[n], acc[m][n], 0, 0, 0);
  }
#pragma unroll
  for (int m = 0; m < 2; ++m)
#pragma unroll
    for (int n = 0; n < 2; ++n) {
      int c = n * 16 + lr;
      int t = c >> 3, jj = c & 7, head = jj & 3;
      float* dstp = (jj & 4) ? ad_ : as_;
#pragma unroll
      for (int r = 0; r < 4; ++r) {
        int gr = n0 + wid * 32 + m * 16 + lg * 4 + r;
        if (gr < N) dstp[((size_t)t * N + gr) * 4 + head] = acc[m][n][r];
      }
    }
}

// ======== scatter + per-edge softmax weights (q) precompute
__global__ __launch_bounds__(256) void scatter_q_kernel(
    const int* __restrict__ src, const int* __restrict__ dst,
    const int* __restrict__ attr, int* __restrict__ cursor,
    int* __restrict__ slist, float* __restrict__ qlist,
    const float* __restrict__ as_, const float* __restrict__ ad_,
    int E, int N) {
  int e = blockIdx.x * 256 + threadIdx.x;
  if (e >= E) return;
  int t = attr[e], s = src[e], d = dst[e];
  int p = atomicAdd(&cursor[(size_t)t * N + d], 1);
  float4 a = *(const float4*)(as_ + ((size_t)t * N + s) * 4);
  float4 b = *(const float4*)(ad_ + ((size_t)t * N + d) * 4);
  float4 q;
  q.x = __expf(lrelu(a.x + b.x));
  q.y = __expf(lrelu(a.y + b.y));
  q.z = __expf(lrelu(a.z + b.z));
  q.w = __expf(lrelu(a.w + b.w));
  slist[p] = s;
  *(float4*)(qlist + (size_t)p * 4) = q;
}

// ======== FUSED gather + GEMM + LayerNorm + ReLU.
// Block = 32 nodes, 256 threads. Per type t: gather agg slice [32][512] bf16
// into LDS (XOR-swizzled), then accumulate [32x512]@G_t[512x128] via MFMA,
// B staged per K=128 chunk (r13 prefetch-regs protocol). LN via LDS bounce.
__global__ __launch_bounds__(256) void fused_kernel(
    const int* __restrict__ slist, const float* __restrict__ qlist,
    const int* __restrict__ rowptr, const int* __restrict__ deg,
    const float* __restrict__ as_, const float* __restrict__ ad_,
    const unsigned short* __restrict__ xb, const unsigned short* __restrict__ Gfrag,
    const float* __restrict__ cbias, const float* __restrict__ gamma,
    const float* __restrict__ beta, float* __restrict__ out, int N) {
  __shared__ __align__(16) unsigned char agg_lds[32 * 1024];  // 32KB agg tile
  __shared__ uint4 blds[2048];                                // 32KB B chunk
  const int tid = threadIdx.x, lane = tid & 63, wid = tid >> 6;
  const int n0 = blockIdx.x * 32;
  const int u = lane >> 4, c16 = lane & 15;
  const int lr = lane & 15, lg = lane >> 4;
  const int rw = wid & 1, cw = wid >> 1;

  uint4 breg[8];
#pragma unroll
  for (int jj = 0; jj < 8; ++jj)
    breg[jj] = *(const uint4*)(Gfrag + (size_t)(jj * 256 + tid) * 8);

  f32x4 acc[4] = {};
  for (int g = 0; g < 16; ++g) {
    // (1) commit staged B chunk g to LDS (prev chunk fully consumed: bar (6))
#pragma unroll
    for (int jj = 0; jj < 8; ++jj) blds[jj * 256 + tid] = breg[jj];
    // (2) type boundary: rebuild agg tile for t = g>>2
    if ((g & 3) == 0) {
      int t = g >> 2;
      size_t tn = (size_t)t * N;
      for (int r = 0; r < 2; ++r) {
        int row = r * 16 + wid * 4 + u;
        int d = n0 + row;
        int swz = (row & 7) << 4;
        int dofs = c16 * 8;
        if (d >= N) {
          uint4v z = {0, 0, 0, 0};
#pragma unroll
          for (int h = 0; h < 4; ++h)
            *(uint4v*)(agg_lds + ((row * 1024 + h * 256 + c16 * 16) ^ swz)) = z;
          continue;
        }
        int base = rowptr[tn + d], dg = deg[tn + d];
        uint4v uself = *(const uint4v*)(xb + (size_t)d * DD + dofs);
        if (dg == 0) {
#pragma unroll
          for (int h = 0; h < 4; ++h)
            *(uint4v*)(agg_lds + ((row * 1024 + h * 256 + c16 * 16) ^ swz)) = uself;
          continue;
        }
        float4 ad4 = *(const float4*)(ad_ + (tn + d) * 4);
        float4 av = *(const float4*)(as_ + (tn + d) * 4);
        float den[4], hv[8], gac[4][8];
        {
          float qs[4];
          qs[0] = __expf(lrelu(av.x + ad4.x));
          qs[1] = __expf(lrelu(av.y + ad4.y));
          qs[2] = __expf(lrelu(av.z + ad4.z));
          qs[3] = __expf(lrelu(av.w + ad4.w));
          unpack8v(uself, hv);
#pragma unroll
          for (int h = 0; h < 4; ++h) {
            den[h] = qs[h];
#pragma unroll
            for (int j = 0; j < 8; ++j) gac[h][j] = qs[h] * hv[j];
          }
        }
        int i = 0;
        for (; i + 1 < dg; i += 2) {
          int s0 = slist[base + i], s1 = slist[base + i + 1];
          float4 q0 = *(const float4*)(qlist + (size_t)(base + i) * 4);
          float4 q1 = *(const float4*)(qlist + (size_t)(base + i + 1) * 4);
          uint4v u0 = *(const uint4v*)(xb + (size_t)s0 * DD + dofs);
          uint4v u1 = *(const uint4v*)(xb + (size_t)s1 * DD + dofs);
          float qa[4] = {q0.x, q0.y, q0.z, q0.w};
          float qb[4] = {q1.x, q1.y, q1.z, q1.w};
#pragma unroll
          for (int h = 0; h < 4; ++h) den[h] += qa[h] + qb[h];
          unpack8v(u0, hv);
#pragma unroll
          for (int h = 0; h < 4; ++h)
#pragma unroll
            for (int j = 0; j < 8; ++j) gac[h][j] += qa[h] * hv[j];
          unpack8v(u1, hv);
#pragma unroll
          for (int h = 0; h < 4; ++h)
#pragma unroll
            for (int j = 0; j < 8; ++j) gac[h][j] += qb[h] * hv[j];
        }
        if (i < dg) {
          int s = slist[base + i];
          float4 q = *(const float4*)(qlist + (size_t)(base + i) * 4);
          uint4v ue = *(const uint4v*)(xb + (size_t)s * DD + dofs);
          float qe[4] = {q.x, q.y, q.z, q.w};
#pragma unroll
          for (int h = 0; h < 4; ++h) den[h] += qe[h];
          unpack8v(ue, hv);
#pragma unroll
          for (int h = 0; h < 4; ++h)
#pragma unroll
            for (int j = 0; j < 8; ++j) gac[h][j] += qe[h] * hv[j];
        }
#pragma unroll
        for (int h = 0; h < 4; ++h) {
          float rd = 1.f / den[h];
          uint4v o;
          o.x = (unsigned)f2b(gac[h][0] * rd) | ((unsigned)f2b(gac[h][1] * rd) << 16);
          o.y = (unsigned)f2b(gac[h][2] * rd) | ((unsigned)f2b(gac[h][3] * rd) << 16);
          o.z = (unsigned)f2b(gac[h][4] * rd) | ((unsigned)f2b(gac[h][5] * rd) << 16);
          o.w = (unsigned)f2b(gac[h][6] * rd) | ((unsigned)f2b(gac[h][7] * rd) << 16);
          *(uint4v*)(agg_lds + ((row * 1024 + h * 256 + c16 * 16) ^ swz)) = o;
        }
      }
    }
    __syncthreads();  // (3) agg + B visible
    // (4) MFMA: 4 k-steps of this chunk; wave = rows rw*16.., cols cw*64..
    {
      const unsigned char* bl = (const unsigned char*)blds;
      int arow = rw * 16 + lr;
      int aswz = (arow & 7) << 4;
#pragma unroll
      for (int ks = 0; ks < 4; ++ks) {
        int ksg = (g & 3) * 4 + ks;
        short8 a = *(const short8*)(agg_lds + ((arow * 1024 + ksg * 64 + lg * 16) ^ aswz));
#pragma unroll
        for (int nn = 0; nn < 4; ++nn) {
          short8 b = *(const short8*)(bl + (ks * 8 + cw * 4 + nn) * 1024 + lane * 16);
          acc[nn] = __builtin_amdgcn_mfma_f32_16x16x32_bf16(a, b, acc[nn], 0, 0, 0);
        }
      }
    }
    // (5) prefetch next B chunk
    if (g < 15) {
#pragma unroll
      for (int jj = 0; jj < 8; ++jj)
        breg[jj] = *(const uint4*)(Gfrag + (size_t)(g + 1) * 16384 +
                                   (size_t)(jj * 256 + tid) * 8);
    }
    __syncthreads();  // (6) all waves done reading blds + agg
  }

  // ---- epilogue: cross-wave LayerNorm + ReLU
  float* lnp = (float*)agg_lds;   // 128 floats used; agg dead
  float cb[4], gm[4], bt[4];
#pragma unroll
  for (int nn = 0; nn < 4; ++nn) {
    int col = cw * 64 + nn * 16 + lr;
    cb[nn] = cbias[col];
    gm[nn] = gamma[col];
    bt[nn] = beta[col];
  }
#pragma unroll
  for (int rr = 0; rr < 4; ++rr) {
    float s = 0.f, ss = 0.f;
#pragma unroll
    for (int nn = 0; nn < 4; ++nn) {
      float y = acc[nn][rr] + cb[nn];
      s += y;
      ss += y * y;
    }
    s += __shfl_xor(s, 1); ss += __shfl_xor(ss, 1);
    s += __shfl_xor(s, 2); ss += __shfl_xor(ss, 2);
    s += __shfl_xor(s, 4); ss += __shfl_xor(ss, 4);
    s += __shfl_xor(s, 8); ss += __shfl_xor(ss, 8);
    if (lr == 0) {
      int row32 = rw * 16 + lg * 4 + rr;
      lnp[cw * 32 + row32] = s;
      lnp[64 + cw * 32 + row32] = ss;
    }
  }
  __syncthreads();
#pragma unroll
  for (int rr = 0; rr < 4; ++rr) {
    int row32 = rw * 16 + lg * 4 + rr;
    int orow = n0 + row32;
    if (orow < N) {
      float st = lnp[row32] + lnp[32 + row32];
      float sst = lnp[64 + row32] + lnp[96 + row32];
      float mean = st * (1.f / 128.f);
      float var = sst * (1.f / 128.f) - mean * mean;
      float rstd = rsqrtf(var + 1e-5f);
#pragma unroll
      for (int nn = 0; nn < 4; ++nn) {
        float v = (acc[nn][rr] + cb[nn] - mean) * rstd * gm[nn] + bt[nn];
        out[(size_t)orow * DD + cw * 64 + nn * 16 + lr] = fmaxf(0.f, v);
      }
    }
  }
}

extern "C" void kernel_launch(void* const* d_in, const int* in_sizes, int n_in,
                              void* d_out, int out_size, void* d_ws, size_t ws_size,
                              hipStream_t stream) {
  const float* x      = (const float*)d_in[0];
  const int*   ei     = (const int*)d_in[1];
  const int*   attr   = (const int*)d_in[2];
  const float* Wg     = (const float*)d_in[3];
  const float* a_src  = (const float*)d_in[4];
  const float* a_dst  = (const float*)d_in[5];
  const float* b_gat  = (const float*)d_in[6];
  const float* etw    = (const float*)d_in[7];
  const float* W_fuse = (const float*)d_in[8];
  const float* b_fuse = (const float*)d_in[9];
  const float* gamma  = (const float*)d_in[10];
  const float* beta   = (const float*)d_in[11];

  const int N = in_sizes[0] / DD;
  const int E = in_sizes[2];
  const int* src = ei;
  const int* dst = ei + E;
  const int M = TT * N;

  char* ws = (char*)d_ws;
  size_t off = 0;
  auto alloc = [&](size_t bytes) {
    void* p = ws + off;
    off += (bytes + 255) & ~(size_t)255;
    return p;
  };
  unsigned short* xb    = (unsigned short*)alloc((size_t)N * DD * 2);        // 12.8MB
  unsigned short* Gfrag = (unsigned short*)alloc((size_t)512 * 512 * 2);     // 512KB
  unsigned short* Pall  = (unsigned short*)alloc((size_t)32 * DD * 2);       // 8KB
  float* cbias          = (float*)alloc(128 * sizeof(float));
  float* as_            = (float*)alloc((size_t)TT * N * 4 * sizeof(float)); // 3.2MB
  float* ad_            = (float*)alloc((size_t)TT * N * 4 * sizeof(float));
  int* deg              = (int*)alloc((size_t)(M + 1) * sizeof(int));        // +1 = gcur
  int* rowptr           = (int*)alloc((size_t)M * sizeof(int));
  int* cursor           = (int*)alloc((size_t)M * sizeof(int));
  int* slist            = (int*)alloc((size_t)E * sizeof(int));              // 1.3MB
  float* qlist          = (float*)alloc((size_t)E * 4 * sizeof(float));      // 5.1MB

  hipMemsetAsync(deg, 0, (size_t)(M + 1) * sizeof(int), stream);

  int total4x = N * DD / 4;
  int nconv = (total4x + 255) / 256;
  int nhist = (E + 255) / 256;
  prologue_kernel<<<nconv + 17 + nhist, 256, 0, stream>>>(
      x, xb, total4x, Wg, a_src, a_dst, W_fuse, b_gat, etw, b_fuse,
      Pall, cbias, dst, attr, deg, E, N);

  int nscan = (M + 255) / 256;
  int nalpha = (N + 127) / 128;
  stage2_kernel<<<nscan + 256 + nalpha, 256, 0, stream>>>(
      deg, rowptr, cursor, deg + M, M, Wg, W_fuse, etw, Gfrag,
      xb, Pall, as_, ad_, N);

  scatter_q_kernel<<<nhist, 256, 0, stream>>>(src, dst, attr, cursor, slist,
                                              qlist, as_, ad_, E, N);

  fused_kernel<<<(N + 31) / 32, 256, 0, stream>>>(
      slist, qlist, rowptr, deg, as_, ad_, xb, Gfrag, cbias, gamma, beta,
      (float*)d_out, N);
}

// Round 16
// 230.268 us; speedup vs baseline: 1.7582x; 1.7582x over previous
//
#include <hip/hip_runtime.h>
#include <hip/hip_bf16.h>

#define TT 4
#define HH 4
#define DD 128
#define KAGG 2048   // TT * HH * DD

typedef __attribute__((ext_vector_type(8))) short short8;
typedef __attribute__((ext_vector_type(4))) float f32x4;
typedef __attribute__((ext_vector_type(4))) unsigned int uint4v;

__device__ __forceinline__ float lrelu(float z) { return z > 0.f ? z : 0.2f * z; }
__device__ __forceinline__ float bf2f(unsigned short u) {
  union { unsigned int i; float f; } v; v.i = ((unsigned int)u) << 16; return v.f;
}
__device__ __forceinline__ unsigned short f2b(float f) {
  union { float f; unsigned int i; } u; u.f = f;
  unsigned int r = u.i + 0x7fff + ((u.i >> 16) & 1);
  return (unsigned short)(r >> 16);
}
__device__ __forceinline__ void unpack8v(uint4v u, float* hv) {
  hv[0] = bf2f((unsigned short)(u.x & 0xffff));
  hv[1] = bf2f((unsigned short)(u.x >> 16));
  hv[2] = bf2f((unsigned short)(u.y & 0xffff));
  hv[3] = bf2f((unsigned short)(u.y >> 16));
  hv[4] = bf2f((unsigned short)(u.z & 0xffff));
  hv[5] = bf2f((unsigned short)(u.z >> 16));
  hv[6] = bf2f((unsigned short)(u.w & 0xffff));
  hv[7] = bf2f((unsigned short)(u.w >> 16));
}

// ======== prologue: convx | Pall | cbias | hist
__global__ __launch_bounds__(256) void prologue_kernel(
    const float* __restrict__ x, unsigned short* __restrict__ xb, int total4,
    const float* __restrict__ Wg, const float* __restrict__ a_s,
    const float* __restrict__ a_d, const float* __restrict__ W_fuse,
    const float* __restrict__ b_gat, const float* __restrict__ etw,
    const float* __restrict__ b_fuse, unsigned short* __restrict__ Pall,
    float* __restrict__ cbias, const int* __restrict__ dst,
    const int* __restrict__ attr, int* __restrict__ deg, int E, int N) {
  int bid = blockIdx.x;
  const int nconv = (total4 + 255) >> 8;
  if (bid < nconv) {                       // ---- convx
    int i = bid * 256 + threadIdx.x;
    if (i < total4) {
      float4 v = ((const float4*)x)[i];
      ushort4 o;
      o.x = f2b(v.x); o.y = f2b(v.y); o.z = f2b(v.z); o.w = f2b(v.w);
      ((ushort4*)xb)[i] = o;
    }
    return;
  }
  bid -= nconv;
  if (bid < 17) {
    float e0 = etw[0], e1 = etw[1], e2 = etw[2], e3 = etw[3];
    float mx = fmaxf(fmaxf(e0, e1), fmaxf(e2, e3));
    float w0 = __expf(e0 - mx), w1 = __expf(e1 - mx), w2 = __expf(e2 - mx),
          w3 = __expf(e3 - mx);
    float inv = 1.f / (w0 + w1 + w2 + w3);
    float wts[4] = {w0 * inv, w1 * inv, w2 * inv, w3 * inv};
    if (bid < 16) {                        // ---- Pall: 32*128
      int idx = bid * 256 + threadIdx.x;
      int c = idx >> 7, k = idx & 127;
      int t = c >> 3, jj = c & 7, head = jj & 3;
      const float* av = ((jj < 4) ? a_s : a_d) + (t * 4 + head) * 128;
      const float* wr = Wg + (size_t)t * 65536 + k * 512 + head * 128;
      float s = 0.f;
      for (int m = 0; m < 128; ++m) s += wr[m] * av[m];
      Pall[c * 128 + k] = f2b(s);
    } else {                               // ---- cbias
      int j = threadIdx.x;
      if (j < 128) {
        float s = b_fuse[j];
        for (int t = 0; t < 4; ++t) {
          float st = 0.f;
          for (int m = 0; m < 128; ++m)
            st += b_gat[t * 128 + m] * W_fuse[(size_t)(t * 128 + m) * 128 + j];
          s += wts[t] * st;
        }
        cbias[j] = s;
      }
    }
    return;
  }
  bid -= 17;                               // ---- hist
  int e = bid * 256 + threadIdx.x;
  if (e < E) atomicAdd(&deg[attr[e] * N + dst[e]], 1);
}

// ======== Gfrag prep with LDS-cached W_fuse_t (coalesced everywhere)
__global__ __launch_bounds__(256) void gprep_kernel(
    const float* __restrict__ Wg, const float* __restrict__ W_fuse,
    const float* __restrict__ etw, unsigned short* __restrict__ Gfrag) {
  __shared__ float Bs[128][128];  // 64KB: W_fuse_t [m][j]
  int t = blockIdx.x >> 6;
  int kr0 = (blockIdx.x & 63) * 8;
  const float* wf = W_fuse + (size_t)t * 16384;
#pragma unroll
  for (int i = 0; i < 64; ++i)
    ((float*)Bs)[i * 256 + threadIdx.x] = wf[i * 256 + threadIdx.x];

  float e0 = etw[0], e1 = etw[1], e2 = etw[2], e3 = etw[3];
  float mx = fmaxf(fmaxf(e0, e1), fmaxf(e2, e3));
  float w0 = __expf(e0 - mx), w1 = __expf(e1 - mx), w2 = __expf(e2 - mx),
        w3 = __expf(e3 - mx);
  float inv = 1.f / (w0 + w1 + w2 + w3);
  float wt = ((t == 0) ? w0 : (t == 1) ? w1 : (t == 2) ? w2 : w3) * inv * 0.25f;
  __syncthreads();

  int rr = threadIdx.x >> 7;      // 0..1
  int j  = threadIdx.x & 127;
#pragma unroll
  for (int r2 = 0; r2 < 4; ++r2) {
    int kr = kr0 + r2 * 2 + rr;   // 0..511 (= head*128 + k)
    int head = kr >> 7, k = kr & 127;
    const float* wr = Wg + (size_t)t * 65536 + k * 512 + head * 128;
    float s = 0.f;
    for (int m = 0; m < 128; ++m) s += wr[m] * Bs[m][j];
    s *= wt;
    int K = t * 512 + kr;
    int kt = K >> 7, kk = (K >> 5) & 3, n = j >> 4;
    int f = (kt * 4 + kk) * 8 + n;
    int lg = (K >> 3) & 3, lr = j & 15, j8 = K & 7;
    Gfrag[(size_t)f * 512 + (lg * 16 + lr) * 8 + j8] = f2b(s);
  }
}

// ======== single-pass scan: block-local scan + atomic chunk-base allocation.
__global__ __launch_bounds__(1024) void scanfused_kernel(
    const int* __restrict__ deg, int* __restrict__ rowptr,
    int* __restrict__ cursor, int* __restrict__ gcur, int M) {
  __shared__ int sh[1024];
  __shared__ int base;
  int i = blockIdx.x * 1024 + threadIdx.x;
  int v = (i < M) ? deg[i] : 0;
  sh[threadIdx.x] = v;
  __syncthreads();
  for (int off = 1; off < 1024; off <<= 1) {
    int xx = (threadIdx.x >= off) ? sh[threadIdx.x - off] : 0;
    __syncthreads();
    sh[threadIdx.x] += xx;
    __syncthreads();
  }
  if (threadIdx.x == 1023) base = atomicAdd(gcur, sh[1023]);
  __syncthreads();
  if (i < M) {
    int r = base + sh[threadIdx.x] - v;
    rowptr[i] = r;
    cursor[i] = r;
  }
}

// ======== scatter | alpha (merged)
__global__ __launch_bounds__(256) void scatter_alpha_kernel(
    const int* __restrict__ src, const int* __restrict__ dst,
    const int* __restrict__ attr, int* __restrict__ cursor,
    int* __restrict__ slist, const unsigned short* __restrict__ xb,
    const unsigned short* __restrict__ Pall, float* __restrict__ as_,
    float* __restrict__ ad_, int E, int N) {
  __shared__ uint4 ldsv[2048];  // 32KB (alpha branch only)
  int bid = blockIdx.x;
  const int nsc = (E + 255) >> 8;
  if (bid < nsc) {                         // ---- scatter
    int e = bid * 256 + threadIdx.x;
    if (e < E) {
      int p = atomicAdd(&cursor[attr[e] * N + dst[e]], 1);
      slist[p] = src[e];
    }
    return;
  }
  bid -= nsc;                              // ---- alpha via MFMA
  unsigned char* lds = (unsigned char*)ldsv;
  const int n0 = bid * 128;
  const int tid = threadIdx.x, lane = tid & 63, wid = tid >> 6;
  const int lr = lane & 15, lg = lane >> 4;
#pragma unroll
  for (int i = 0; i < 8; ++i) {
    int chunk = tid + i * 256;
    int row = chunk >> 4, k16 = chunk & 15;
    int gr = n0 + row;
    uint4 v = make_uint4(0, 0, 0, 0);
    if (gr < N) v = *(const uint4*)(xb + (size_t)gr * DD + k16 * 8);
    *(uint4*)(lds + ((row * 256 + k16 * 16) ^ ((row & 7) << 4))) = v;
  }
  __syncthreads();
  f32x4 acc[2][2] = {};
#pragma unroll
  for (int kk = 0; kk < 4; ++kk) {
    short8 a[2], b[2];
#pragma unroll
    for (int m = 0; m < 2; ++m) {
      int row = wid * 32 + m * 16 + lr;
      a[m] = *(const short8*)(lds + ((row * 256 + kk * 64 + (lg << 4)) ^ ((row & 7) << 4)));
    }
#pragma unroll
    for (int n = 0; n < 2; ++n) {
      int c = n * 16 + lr;
      b[n] = *(const short8*)(Pall + c * DD + kk * 32 + lg * 8);
    }
#pragma unroll
    for (int m = 0; m < 2; ++m)
#pragma unroll
      for (int n = 0; n < 2; ++n)
        acc[m][n] = __builtin_amdgcn_mfma_f32_16x16x32_bf16(a[m], b[n], acc[m][n], 0, 0, 0);
  }
#pragma unroll
  for (int m = 0; m < 2; ++m)
#pragma unroll
    for (int n = 0; n < 2; ++n) {
      int c = n * 16 + lr;
      int t = c >> 3, jj = c & 7, head = jj & 3;
      float* dstp = (jj & 4) ? ad_ : as_;
#pragma unroll
      for (int r = 0; r < 4; ++r) {
        int gr = n0 + wid * 32 + m * 16 + lg * 4 + r;
        if (gr < N) dstp[((size_t)t * N + gr) * 4 + head] = acc[m][n][r];
      }
    }
}

// ======== gather: 16 lanes per (t,d) unit, 4 units/wave, 2-wide unroll (r11)
__global__ __launch_bounds__(256) void gather_kernel(
    const int* __restrict__ slist, const int* __restrict__ rowptr,
    const int* __restrict__ deg, const float* __restrict__ as_,
    const float* __restrict__ ad_, const unsigned short* __restrict__ xb,
    unsigned short* __restrict__ AGG, int N) {
  int t = blockIdx.y;
  int lane = threadIdx.x & 63;
  int u = lane >> 4, c16 = lane & 15;
  int d = blockIdx.x * 16 + (threadIdx.x >> 6) * 4 + u;
  if (d >= N) return;
  size_t tn = (size_t)t * N;
  int dofs = c16 * 8;
  unsigned short* outp = AGG + (size_t)d * KAGG + t * 512 + dofs;

  int base = rowptr[tn + d], dg = deg[tn + d];
  uint4v uself = *(const uint4v*)(xb + (size_t)d * DD + dofs);
  if (dg == 0) {   // softmax over {self} = 1 -> AGG slice = xb slice, all heads
#pragma unroll
    for (int h = 0; h < 4; ++h) *(uint4v*)(outp + h * DD) = uself;
    return;
  }

  float4 ad4 = *(const float4*)(ad_ + (tn + d) * 4);
  float4 av = *(const float4*)(as_ + (tn + d) * 4);
  float q[4], den[4], hv[8], acc[4][8];
  q[0] = __expf(lrelu(av.x + ad4.x));
  q[1] = __expf(lrelu(av.y + ad4.y));
  q[2] = __expf(lrelu(av.z + ad4.z));
  q[3] = __expf(lrelu(av.w + ad4.w));
  unpack8v(uself, hv);
#pragma unroll
  for (int h = 0; h < 4; ++h) {
    den[h] = q[h];
#pragma unroll
    for (int j = 0; j < 8; ++j) acc[h][j] = q[h] * hv[j];
  }

  int i = 0;
  for (; i + 1 < dg; i += 2) {
    int s0 = slist[base + i], s1 = slist[base + i + 1];
    float4 a0 = *(const float4*)(as_ + (tn + s0) * 4);
    float4 a1 = *(const float4*)(as_ + (tn + s1) * 4);
    uint4v u0 = *(const uint4v*)(xb + (size_t)s0 * DD + dofs);
    uint4v u1 = *(const uint4v*)(xb + (size_t)s1 * DD + dofs);
    float q0[4], q1[4];
    q0[0] = __expf(lrelu(a0.x + ad4.x));
    q0[1] = __expf(lrelu(a0.y + ad4.y));
    q0[2] = __expf(lrelu(a0.z + ad4.z));
    q0[3] = __expf(lrelu(a0.w + ad4.w));
    q1[0] = __expf(lrelu(a1.x + ad4.x));
    q1[1] = __expf(lrelu(a1.y + ad4.y));
    q1[2] = __expf(lrelu(a1.z + ad4.z));
    q1[3] = __expf(lrelu(a1.w + ad4.w));
#pragma unroll
    for (int h = 0; h < 4; ++h) den[h] += q0[h] + q1[h];
    unpack8v(u0, hv);
#pragma unroll
    for (int h = 0; h < 4; ++h)
#pragma unroll
      for (int j = 0; j < 8; ++j) acc[h][j] += q0[h] * hv[j];
    unpack8v(u1, hv);
#pragma unroll
    for (int h = 0; h < 4; ++h)
#pragma unroll
      for (int j = 0; j < 8; ++j) acc[h][j] += q1[h] * hv[j];
  }
  if (i < dg) {
    int s = slist[base + i];
    float4 a = *(const float4*)(as_ + (tn + s) * 4);
    uint4v ue = *(const uint4v*)(xb + (size_t)s * DD + dofs);
    float qe[4];
    qe[0] = __expf(lrelu(a.x + ad4.x));
    qe[1] = __expf(lrelu(a.y + ad4.y));
    qe[2] = __expf(lrelu(a.z + ad4.z));
    qe[3] = __expf(lrelu(a.w + ad4.w));
#pragma unroll
    for (int h = 0; h < 4; ++h) den[h] += qe[h];
    unpack8v(ue, hv);
#pragma unroll
    for (int h = 0; h < 4; ++h)
#pragma unroll
      for (int j = 0; j < 8; ++j) acc[h][j] += qe[h] * hv[j];
  }

#pragma unroll
  for (int h = 0; h < 4; ++h) {
    float r = 1.f / den[h];
    uint4v o;
    o.x = (unsigned)f2b(acc[h][0] * r) | ((unsigned)f2b(acc[h][1] * r) << 16);
    o.y = (unsigned)f2b(acc[h][2] * r) | ((unsigned)f2b(acc[h][3] * r) << 16);
    o.z = (unsigned)f2b(acc[h][4] * r) | ((unsigned)f2b(acc[h][5] * r) << 16);
    o.w = (unsigned)f2b(acc[h][6] * r) | ((unsigned)f2b(acc[h][7] * r) << 16);
    *(uint4v*)(outp + h * DD) = o;
  }
}

// ======== final GEMM [N,2048]@[2048,128] + cbias + LayerNorm + ReLU
// 64 rows/block, 8 waves (512 thr): 4 row-groups x 2 col-halves.
// B staged as 16KB half-kt tiles, dbuf; A reg-prefetched. ~24 waves/CU.
__global__ __launch_bounds__(512) void gemmln_kernel(
    const unsigned short* __restrict__ AGG, const unsigned short* __restrict__ Gfrag,
    const float* __restrict__ cbias, const float* __restrict__ gamma,
    const float* __restrict__ beta, float* __restrict__ out, int N) {
  __shared__ uint4 bbuf[2][1024];   // 2 x 16KB B half-tiles (K=64 each)
  __shared__ float lnbuf[256];
  const int tid = threadIdx.x, lane = tid & 63, wid = tid >> 6;
  const int lr = lane & 15, lg = lane >> 4;
  const int rw = wid & 3, cw = wid >> 2;
  const int n0 = blockIdx.x * 64;
  const int gr = n0 + rw * 16 + lr;
  const bool ok = gr < N;
  const unsigned short* arow = AGG + (size_t)gr * KAGG;

  uint4 bn[2], an[2], ac[2];
#pragma unroll
  for (int i = 0; i < 2; ++i)
    bn[i] = *(const uint4*)(Gfrag + (size_t)(i * 512 + tid) * 8);
#pragma unroll
  for (int kkh = 0; kkh < 2; ++kkh) {
    an[kkh] = make_uint4(0, 0, 0, 0);
    if (ok) an[kkh] = *(const uint4*)(arow + kkh * 32 + lg * 8);
  }
#pragma unroll
  for (int i = 0; i < 2; ++i) bbuf[0][i * 512 + tid] = bn[i];
  ac[0] = an[0]; ac[1] = an[1];
  __syncthreads();

  f32x4 acc[4] = {};
  int cur = 0;
  for (int ht = 0; ht < 32; ++ht) {        // 32 half-tiles of K=64
    if (ht < 31) {                          // prefetch next half
#pragma unroll
      for (int i = 0; i < 2; ++i)
        bn[i] = *(const uint4*)(Gfrag + (size_t)(ht + 1) * 8192 +
                                (size_t)(i * 512 + tid) * 8);
#pragma unroll
      for (int kkh = 0; kkh < 2; ++kkh) {
        an[kkh] = make_uint4(0, 0, 0, 0);
        if (ok) an[kkh] = *(const uint4*)(arow + (ht + 1) * 64 + kkh * 32 + lg * 8);
      }
    }
    const unsigned char* lds = (const unsigned char*)bbuf[cur];
#pragma unroll
    for (int kkh = 0; kkh < 2; ++kkh) {
      short8 a = *(const short8*)&ac[kkh];
#pragma unroll
      for (int n = 0; n < 4; ++n) {
        short8 b = *(const short8*)(lds + (kkh * 8 + cw * 4 + n) * 1024 + lane * 16);
        acc[n] = __builtin_amdgcn_mfma_f32_16x16x32_bf16(a, b, acc[n], 0, 0, 0);
      }
    }
    if (ht < 31) {
#pragma unroll
      for (int i = 0; i < 2; ++i) bbuf[cur ^ 1][i * 512 + tid] = bn[i];
      ac[0] = an[0]; ac[1] = an[1];
      __syncthreads();
      cur ^= 1;
    }
  }

  // ---- LN: per-wave partial over its 64 cols, combine halves via LDS
  float cb[4], gm[4], bt[4];
#pragma unroll
  for (int n = 0; n < 4; ++n) {
    int col = cw * 64 + n * 16 + lr;
    cb[n] = cbias[col];
    gm[n] = gamma[col];
    bt[n] = beta[col];
  }
#pragma unroll
  for (int rr = 0; rr < 4; ++rr) {
    float s = 0.f, ss = 0.f;
#pragma unroll
    for (int n = 0; n < 4; ++n) {
      float y = acc[n][rr] + cb[n];
      s += y;
      ss += y * y;
    }
    s += __shfl_xor(s, 1); ss += __shfl_xor(ss, 1);
    s += __shfl_xor(s, 2); ss += __shfl_xor(ss, 2);
    s += __shfl_xor(s, 4); ss += __shfl_xor(ss, 4);
    s += __shfl_xor(s, 8); ss += __shfl_xor(ss, 8);
    if (lr == 0) {
      int row64 = rw * 16 + lg * 4 + rr;
      lnbuf[cw * 64 + row64] = s;
      lnbuf[128 + cw * 64 + row64] = ss;
    }
  }
  __syncthreads();
#pragma unroll
  for (int rr = 0; rr < 4; ++rr) {
    int row64 = rw * 16 + lg * 4 + rr;
    int orow = n0 + row64;
    if (orow < N) {
      float st = lnbuf[row64] + lnbuf[64 + row64];
      float sst = lnbuf[128 + row64] + lnbuf[192 + row64];
      float mean = st * (1.f / 128.f);
      float var = sst * (1.f / 128.f) - mean * mean;
      float rstd = rsqrtf(var + 1e-5f);
#pragma unroll
      for (int n = 0; n < 4; ++n) {
        float v = (acc[n][rr] + cb[n] - mean) * rstd * gm[n] + bt[n];
        out[(size_t)orow * DD + cw * 64 + n * 16 + lr] = fmaxf(0.f, v);
      }
    }
  }
}

extern "C" void kernel_launch(void* const* d_in, const int* in_sizes, int n_in,
                              void* d_out, int out_size, void* d_ws, size_t ws_size,
                              hipStream_t stream) {
  const float* x      = (const float*)d_in[0];
  const int*   ei     = (const int*)d_in[1];
  const int*   attr   = (const int*)d_in[2];
  const float* Wg     = (const float*)d_in[3];
  const float* a_src  = (const float*)d_in[4];
  const float* a_dst  = (const float*)d_in[5];
  const float* b_gat  = (const float*)d_in[6];
  const float* etw    = (const float*)d_in[7];
  const float* W_fuse = (const float*)d_in[8];
  const float* b_fuse = (const float*)d_in[9];
  const float* gamma  = (const float*)d_in[10];
  const float* beta   = (const float*)d_in[11];

  const int N = in_sizes[0] / DD;
  const int E = in_sizes[2];
  const int* src = ei;
  const int* dst = ei + E;
  const int M = TT * N;

  char* ws = (char*)d_ws;
  size_t off = 0;
  auto alloc = [&](size_t bytes) {
    void* p = ws + off;
    off += (bytes + 255) & ~(size_t)255;
    return p;
  };
  unsigned short* AGG   = (unsigned short*)alloc((size_t)N * KAGG * 2);      // 204.8MB
  unsigned short* xb    = (unsigned short*)alloc((size_t)N * DD * 2);        // 12.8MB
  unsigned short* Gfrag = (unsigned short*)alloc((size_t)512 * 512 * 2);     // 512KB
  unsigned short* Pall  = (unsigned short*)alloc((size_t)32 * DD * 2);       // 8KB
  float* cbias          = (float*)alloc(128 * sizeof(float));
  float* as_            = (float*)alloc((size_t)TT * N * 4 * sizeof(float)); // 3.2MB
  float* ad_            = (float*)alloc((size_t)TT * N * 4 * sizeof(float));
  int* deg              = (int*)alloc((size_t)(M + 1) * sizeof(int));        // +1 = gcur
  int* rowptr           = (int*)alloc((size_t)M * sizeof(int));
  int* cursor           = (int*)alloc((size_t)M * sizeof(int));
  int* slist            = (int*)alloc((size_t)E * sizeof(int));              // 1.3MB

  hipMemsetAsync(deg, 0, (size_t)(M + 1) * sizeof(int), stream);

  int total4x = N * DD / 4;
  int nconv = (total4x + 255) / 256;
  int nhist = (E + 255) / 256;
  prologue_kernel<<<nconv + 17 + nhist, 256, 0, stream>>>(
      x, xb, total4x, Wg, a_src, a_dst, W_fuse, b_gat, etw, b_fuse,
      Pall, cbias, dst, attr, deg, E, N);

  gprep_kernel<<<256, 256, 0, stream>>>(Wg, W_fuse, etw, Gfrag);

  scanfused_kernel<<<(M + 1023) / 1024, 1024, 0, stream>>>(deg, rowptr, cursor,
                                                           deg + M, M);

  int nalpha = (N + 127) / 128;
  scatter_alpha_kernel<<<nhist + nalpha, 256, 0, stream>>>(
      src, dst, attr, cursor, slist, xb, Pall, as_, ad_, E, N);

  dim3 ggrid((N + 15) / 16, TT);
  gather_kernel<<<ggrid, 256, 0, stream>>>(slist, rowptr, deg, as_, ad_, xb, AGG, N);

  gemmln_kernel<<<(N + 63) / 64, 512, 0, stream>>>(AGG, Gfrag, cbias, gamma, beta,
                                                   (float*)d_out, N);
}

// Round 17
// 202.493 us; speedup vs baseline: 1.9993x; 1.1372x over previous
//
#include <hip/hip_runtime.h>
#include <hip/hip_bf16.h>

#define TT 4
#define HH 4
#define DD 128
#define KAGG 2048   // TT * HH * DD

typedef __attribute__((ext_vector_type(8))) short short8;
typedef __attribute__((ext_vector_type(4))) float f32x4;
typedef __attribute__((ext_vector_type(4))) unsigned int uint4v;

__device__ __forceinline__ float lrelu(float z) { return z > 0.f ? z : 0.2f * z; }
__device__ __forceinline__ float bf2f(unsigned short u) {
  union { unsigned int i; float f; } v; v.i = ((unsigned int)u) << 16; return v.f;
}
__device__ __forceinline__ unsigned short f2b(float f) {
  union { float f; unsigned int i; } u; u.f = f;
  unsigned int r = u.i + 0x7fff + ((u.i >> 16) & 1);
  return (unsigned short)(r >> 16);
}
__device__ __forceinline__ void unpack8v(uint4v u, float* hv) {
  hv[0] = bf2f((unsigned short)(u.x & 0xffff));
  hv[1] = bf2f((unsigned short)(u.x >> 16));
  hv[2] = bf2f((unsigned short)(u.y & 0xffff));
  hv[3] = bf2f((unsigned short)(u.y >> 16));
  hv[4] = bf2f((unsigned short)(u.z & 0xffff));
  hv[5] = bf2f((unsigned short)(u.z >> 16));
  hv[6] = bf2f((unsigned short)(u.w & 0xffff));
  hv[7] = bf2f((unsigned short)(u.w >> 16));
}

// ======== prologue: convx | Pall | cbias | hist
__global__ __launch_bounds__(256) void prologue_kernel(
    const float* __restrict__ x, unsigned short* __restrict__ xb, int total4,
    const float* __restrict__ Wg, const float* __restrict__ a_s,
    const float* __restrict__ a_d, const float* __restrict__ W_fuse,
    const float* __restrict__ b_gat, const float* __restrict__ etw,
    const float* __restrict__ b_fuse, unsigned short* __restrict__ Pall,
    float* __restrict__ cbias, const int* __restrict__ dst,
    const int* __restrict__ attr, int* __restrict__ deg, int E, int N) {
  int bid = blockIdx.x;
  const int nconv = (total4 + 255) >> 8;
  if (bid < nconv) {                       // ---- convx
    int i = bid * 256 + threadIdx.x;
    if (i < total4) {
      float4 v = ((const float4*)x)[i];
      ushort4 o;
      o.x = f2b(v.x); o.y = f2b(v.y); o.z = f2b(v.z); o.w = f2b(v.w);
      ((ushort4*)xb)[i] = o;
    }
    return;
  }
  bid -= nconv;
  if (bid < 17) {
    float e0 = etw[0], e1 = etw[1], e2 = etw[2], e3 = etw[3];
    float mx = fmaxf(fmaxf(e0, e1), fmaxf(e2, e3));
    float w0 = __expf(e0 - mx), w1 = __expf(e1 - mx), w2 = __expf(e2 - mx),
          w3 = __expf(e3 - mx);
    float inv = 1.f / (w0 + w1 + w2 + w3);
    float wts[4] = {w0 * inv, w1 * inv, w2 * inv, w3 * inv};
    if (bid < 16) {                        // ---- Pall: 32*128
      int idx = bid * 256 + threadIdx.x;
      int c = idx >> 7, k = idx & 127;
      int t = c >> 3, jj = c & 7, head = jj & 3;
      const float* av = ((jj < 4) ? a_s : a_d) + (t * 4 + head) * 128;
      const float* wr = Wg + (size_t)t * 65536 + k * 512 + head * 128;
      float s = 0.f;
      for (int m = 0; m < 128; ++m) s += wr[m] * av[m];
      Pall[c * 128 + k] = f2b(s);
    } else {                               // ---- cbias
      int j = threadIdx.x;
      if (j < 128) {
        float s = b_fuse[j];
        for (int t = 0; t < 4; ++t) {
          float st = 0.f;
          for (int m = 0; m < 128; ++m)
            st += b_gat[t * 128 + m] * W_fuse[(size_t)(t * 128 + m) * 128 + j];
          s += wts[t] * st;
        }
        cbias[j] = s;
      }
    }
    return;
  }
  bid -= 17;                               // ---- hist
  int e = bid * 256 + threadIdx.x;
  if (e < E) atomicAdd(&deg[attr[e] * N + dst[e]], 1);
}

// ======== Gfrag prep with LDS-cached W_fuse_t (coalesced everywhere)
__global__ __launch_bounds__(256) void gprep_kernel(
    const float* __restrict__ Wg, const float* __restrict__ W_fuse,
    const float* __restrict__ etw, unsigned short* __restrict__ Gfrag) {
  __shared__ float Bs[128][128];  // 64KB: W_fuse_t [m][j]
  int t = blockIdx.x >> 6;
  int kr0 = (blockIdx.x & 63) * 8;
  const float* wf = W_fuse + (size_t)t * 16384;
#pragma unroll
  for (int i = 0; i < 64; ++i)
    ((float*)Bs)[i * 256 + threadIdx.x] = wf[i * 256 + threadIdx.x];

  float e0 = etw[0], e1 = etw[1], e2 = etw[2], e3 = etw[3];
  float mx = fmaxf(fmaxf(e0, e1), fmaxf(e2, e3));
  float w0 = __expf(e0 - mx), w1 = __expf(e1 - mx), w2 = __expf(e2 - mx),
        w3 = __expf(e3 - mx);
  float inv = 1.f / (w0 + w1 + w2 + w3);
  float wt = ((t == 0) ? w0 : (t == 1) ? w1 : (t == 2) ? w2 : w3) * inv * 0.25f;
  __syncthreads();

  int rr = threadIdx.x >> 7;      // 0..1
  int j  = threadIdx.x & 127;
#pragma unroll
  for (int r2 = 0; r2 < 4; ++r2) {
    int kr = kr0 + r2 * 2 + rr;   // 0..511 (= head*128 + k)
    int head = kr >> 7, k = kr & 127;
    const float* wr = Wg + (size_t)t * 65536 + k * 512 + head * 128;
    float s = 0.f;
    for (int m = 0; m < 128; ++m) s += wr[m] * Bs[m][j];
    s *= wt;
    int K = t * 512 + kr;
    int kt = K >> 7, kk = (K >> 5) & 3, n = j >> 4;
    int f = (kt * 4 + kk) * 8 + n;
    int lg = (K >> 3) & 3, lr = j & 15, j8 = K & 7;
    Gfrag[(size_t)f * 512 + (lg * 16 + lr) * 8 + j8] = f2b(s);
  }
}

// ======== single-pass scan: block-local scan + atomic chunk-base allocation.
__global__ __launch_bounds__(1024) void scanfused_kernel(
    const int* __restrict__ deg, int* __restrict__ rowptr,
    int* __restrict__ cursor, int* __restrict__ gcur, int M) {
  __shared__ int sh[1024];
  __shared__ int base;
  int i = blockIdx.x * 1024 + threadIdx.x;
  int v = (i < M) ? deg[i] : 0;
  sh[threadIdx.x] = v;
  __syncthreads();
  for (int off = 1; off < 1024; off <<= 1) {
    int xx = (threadIdx.x >= off) ? sh[threadIdx.x - off] : 0;
    __syncthreads();
    sh[threadIdx.x] += xx;
    __syncthreads();
  }
  if (threadIdx.x == 1023) base = atomicAdd(gcur, sh[1023]);
  __syncthreads();
  if (i < M) {
    int r = base + sh[threadIdx.x] - v;
    rowptr[i] = r;
    cursor[i] = r;
  }
}

// ======== scatter | alpha (merged)
__global__ __launch_bounds__(256) void scatter_alpha_kernel(
    const int* __restrict__ src, const int* __restrict__ dst,
    const int* __restrict__ attr, int* __restrict__ cursor,
    int* __restrict__ slist, const unsigned short* __restrict__ xb,
    const unsigned short* __restrict__ Pall, float* __restrict__ as_,
    float* __restrict__ ad_, int E, int N) {
  __shared__ uint4 ldsv[2048];  // 32KB (alpha branch only)
  int bid = blockIdx.x;
  const int nsc = (E + 255) >> 8;
  if (bid < nsc) {                         // ---- scatter
    int e = bid * 256 + threadIdx.x;
    if (e < E) {
      int p = atomicAdd(&cursor[attr[e] * N + dst[e]], 1);
      slist[p] = src[e];
    }
    return;
  }
  bid -= nsc;                              // ---- alpha via MFMA
  unsigned char* lds = (unsigned char*)ldsv;
  const int n0 = bid * 128;
  const int tid = threadIdx.x, lane = tid & 63, wid = tid >> 6;
  const int lr = lane & 15, lg = lane >> 4;
#pragma unroll
  for (int i = 0; i < 8; ++i) {
    int chunk = tid + i * 256;
    int row = chunk >> 4, k16 = chunk & 15;
    int gr = n0 + row;
    uint4 v = make_uint4(0, 0, 0, 0);
    if (gr < N) v = *(const uint4*)(xb + (size_t)gr * DD + k16 * 8);
    *(uint4*)(lds + ((row * 256 + k16 * 16) ^ ((row & 7) << 4))) = v;
  }
  __syncthreads();
  f32x4 acc[2][2] = {};
#pragma unroll
  for (int kk = 0; kk < 4; ++kk) {
    short8 a[2], b[2];
#pragma unroll
    for (int m = 0; m < 2; ++m) {
      int row = wid * 32 + m * 16 + lr;
      a[m] = *(const short8*)(lds + ((row * 256 + kk * 64 + (lg << 4)) ^ ((row & 7) << 4)));
    }
#pragma unroll
    for (int n = 0; n < 2; ++n) {
      int c = n * 16 + lr;
      b[n] = *(const short8*)(Pall + c * DD + kk * 32 + lg * 8);
    }
#pragma unroll
    for (int m = 0; m < 2; ++m)
#pragma unroll
      for (int n = 0; n < 2; ++n)
        acc[m][n] = __builtin_amdgcn_mfma_f32_16x16x32_bf16(a[m], b[n], acc[m][n], 0, 0, 0);
  }
#pragma unroll
  for (int m = 0; m < 2; ++m)
#pragma unroll
    for (int n = 0; n < 2; ++n) {
      int c = n * 16 + lr;
      int t = c >> 3, jj = c & 7, head = jj & 3;
      float* dstp = (jj & 4) ? ad_ : as_;
#pragma unroll
      for (int r = 0; r < 4; ++r) {
        int gr = n0 + wid * 32 + m * 16 + lg * 4 + r;
        if (gr < N) dstp[((size_t)t * N + gr) * 4 + head] = acc[m][n][r];
      }
    }
}

// ======== gather: 16 lanes per (t,d) unit, 4 units/wave, 2-wide unroll (r11)
__global__ __launch_bounds__(256) void gather_kernel(
    const int* __restrict__ slist, const int* __restrict__ rowptr,
    const int* __restrict__ deg, const float* __restrict__ as_,
    const float* __restrict__ ad_, const unsigned short* __restrict__ xb,
    unsigned short* __restrict__ AGG, int N) {
  int t = blockIdx.y;
  int lane = threadIdx.x & 63;
  int u = lane >> 4, c16 = lane & 15;
  int d = blockIdx.x * 16 + (threadIdx.x >> 6) * 4 + u;
  if (d >= N) return;
  size_t tn = (size_t)t * N;
  int dofs = c16 * 8;
  unsigned short* outp = AGG + (size_t)d * KAGG + t * 512 + dofs;

  int base = rowptr[tn + d], dg = deg[tn + d];
  uint4v uself = *(const uint4v*)(xb + (size_t)d * DD + dofs);
  if (dg == 0) {   // softmax over {self} = 1 -> AGG slice = xb slice, all heads
#pragma unroll
    for (int h = 0; h < 4; ++h) *(uint4v*)(outp + h * DD) = uself;
    return;
  }

  float4 ad4 = *(const float4*)(ad_ + (tn + d) * 4);
  float4 av = *(const float4*)(as_ + (tn + d) * 4);
  float q[4], den[4], hv[8], acc[4][8];
  q[0] = __expf(lrelu(av.x + ad4.x));
  q[1] = __expf(lrelu(av.y + ad4.y));
  q[2] = __expf(lrelu(av.z + ad4.z));
  q[3] = __expf(lrelu(av.w + ad4.w));
  unpack8v(uself, hv);
#pragma unroll
  for (int h = 0; h < 4; ++h) {
    den[h] = q[h];
#pragma unroll
    for (int j = 0; j < 8; ++j) acc[h][j] = q[h] * hv[j];
  }

  int i = 0;
  for (; i + 1 < dg; i += 2) {
    int s0 = slist[base + i], s1 = slist[base + i + 1];
    float4 a0 = *(const float4*)(as_ + (tn + s0) * 4);
    float4 a1 = *(const float4*)(as_ + (tn + s1) * 4);
    uint4v u0 = *(const uint4v*)(xb + (size_t)s0 * DD + dofs);
    uint4v u1 = *(const uint4v*)(xb + (size_t)s1 * DD + dofs);
    float q0[4], q1[4];
    q0[0] = __expf(lrelu(a0.x + ad4.x));
    q0[1] = __expf(lrelu(a0.y + ad4.y));
    q0[2] = __expf(lrelu(a0.z + ad4.z));
    q0[3] = __expf(lrelu(a0.w + ad4.w));
    q1[0] = __expf(lrelu(a1.x + ad4.x));
    q1[1] = __expf(lrelu(a1.y + ad4.y));
    q1[2] = __expf(lrelu(a1.z + ad4.z));
    q1[3] = __expf(lrelu(a1.w + ad4.w));
#pragma unroll
    for (int h = 0; h < 4; ++h) den[h] += q0[h] + q1[h];
    unpack8v(u0, hv);
#pragma unroll
    for (int h = 0; h < 4; ++h)
#pragma unroll
      for (int j = 0; j < 8; ++j) acc[h][j] += q0[h] * hv[j];
    unpack8v(u1, hv);
#pragma unroll
    for (int h = 0; h < 4; ++h)
#pragma unroll
      for (int j = 0; j < 8; ++j) acc[h][j] += q1[h] * hv[j];
  }
  if (i < dg) {
    int s = slist[base + i];
    float4 a = *(const float4*)(as_ + (tn + s) * 4);
    uint4v ue = *(const uint4v*)(xb + (size_t)s * DD + dofs);
    float qe[4];
    qe[0] = __expf(lrelu(a.x + ad4.x));
    qe[1] = __expf(lrelu(a.y + ad4.y));
    qe[2] = __expf(lrelu(a.z + ad4.z));
    qe[3] = __expf(lrelu(a.w + ad4.w));
#pragma unroll
    for (int h = 0; h < 4; ++h) den[h] += qe[h];
    unpack8v(ue, hv);
#pragma unroll
    for (int h = 0; h < 4; ++h)
#pragma unroll
      for (int j = 0; j < 8; ++j) acc[h][j] += qe[h] * hv[j];
  }

#pragma unroll
  for (int h = 0; h < 4; ++h) {
    float r = 1.f / den[h];
    uint4v o;
    o.x = (unsigned)f2b(acc[h][0] * r) | ((unsigned)f2b(acc[h][1] * r) << 16);
    o.y = (unsigned)f2b(acc[h][2] * r) | ((unsigned)f2b(acc[h][3] * r) << 16);
    o.z = (unsigned)f2b(acc[h][4] * r) | ((unsigned)f2b(acc[h][5] * r) << 16);
    o.w = (unsigned)f2b(acc[h][6] * r) | ((unsigned)f2b(acc[h][7] * r) << 16);
    *(uint4v*)(outp + h * DD) = o;
  }
}

// ======== final GEMM [N,2048]@[2048,128] + cbias + LayerNorm + ReLU
// r14 config: 64 rows/block, 4 waves x 16 rows, B as 16KB half-kt dbuf.
__global__ __launch_bounds__(256) void gemmln_kernel(
    const unsigned short* __restrict__ AGG, const unsigned short* __restrict__ Gfrag,
    const float* __restrict__ cbias, const float* __restrict__ gamma,
    const float* __restrict__ beta, float* __restrict__ out, int N) {
  __shared__ uint4 bbuf[2][1024];   // 2 x 16KB B half-tiles (K=64 each)
  const int n0 = blockIdx.x * 64;
  const int tid = threadIdx.x, lane = tid & 63, wid = tid >> 6;
  const int lr = lane & 15, lg = lane >> 4;
  const int wrow = n0 + wid * 16;
  const int gr = wrow + lr;
  const bool ok = gr < N;
  const unsigned short* arow = AGG + (size_t)gr * KAGG;

  uint4 bn[4], an[2], ac[2];
#pragma unroll
  for (int i = 0; i < 4; ++i)
    bn[i] = *(const uint4*)(Gfrag + (size_t)(i * 256 + tid) * 8);
#pragma unroll
  for (int kkh = 0; kkh < 2; ++kkh) {
    an[kkh] = make_uint4(0, 0, 0, 0);
    if (ok) an[kkh] = *(const uint4*)(arow + kkh * 32 + lg * 8);
  }
#pragma unroll
  for (int i = 0; i < 4; ++i) bbuf[0][i * 256 + tid] = bn[i];
  ac[0] = an[0]; ac[1] = an[1];
  __syncthreads();

  f32x4 acc[8] = {};
  int cur = 0;
  for (int ht = 0; ht < 32; ++ht) {        // 32 half-tiles of K=64
    if (ht < 31) {                          // prefetch next half
#pragma unroll
      for (int i = 0; i < 4; ++i)
        bn[i] = *(const uint4*)(Gfrag + (size_t)(ht + 1) * 8192 +
                                (size_t)(i * 256 + tid) * 8);
#pragma unroll
      for (int kkh = 0; kkh < 2; ++kkh) {
        an[kkh] = make_uint4(0, 0, 0, 0);
        if (ok) an[kkh] = *(const uint4*)(arow + (ht + 1) * 64 + kkh * 32 + lg * 8);
      }
    }
    const unsigned char* lds = (const unsigned char*)bbuf[cur];
#pragma unroll
    for (int kkh = 0; kkh < 2; ++kkh) {
      short8 a = *(const short8*)&ac[kkh];
#pragma unroll
      for (int n = 0; n < 8; ++n) {
        short8 b = *(const short8*)(lds + (kkh * 8 + n) * 1024 + lane * 16);
        acc[n] = __builtin_amdgcn_mfma_f32_16x16x32_bf16(a, b, acc[n], 0, 0, 0);
      }
    }
    if (ht < 31) {
#pragma unroll
      for (int i = 0; i < 4; ++i) bbuf[cur ^ 1][i * 256 + tid] = bn[i];
      ac[0] = an[0]; ac[1] = an[1];
      __syncthreads();
      cur ^= 1;
    }
  }

  float cb[8], gm[8], bt[8];
#pragma unroll
  for (int n = 0; n < 8; ++n) {
    cb[n] = cbias[n * 16 + lr];
    gm[n] = gamma[n * 16 + lr];
    bt[n] = beta[n * 16 + lr];
  }
#pragma unroll
  for (int rr = 0; rr < 4; ++rr) {
    float y[8];
    float s = 0.f, ss = 0.f;
#pragma unroll
    for (int n = 0; n < 8; ++n) {
      y[n] = acc[n][rr] + cb[n];
      s += y[n];
      ss += y[n] * y[n];
    }
#pragma unroll
    for (int mask = 1; mask <= 8; mask <<= 1) {
      s += __shfl_xor(s, mask);
      ss += __shfl_xor(ss, mask);
    }
    float mean = s * (1.f / 128.f);
    float var = ss * (1.f / 128.f) - mean * mean;
    float rstd = rsqrtf(var + 1e-5f);
    int orow = wrow + lg * 4 + rr;
    if (orow < N) {
#pragma unroll
      for (int n = 0; n < 8; ++n) {
        float v = (y[n] - mean) * rstd * gm[n] + bt[n];
        out[(size_t)orow * DD + n * 16 + lr] = fmaxf(0.f, v);
      }
    }
  }
}

extern "C" void kernel_launch(void* const* d_in, const int* in_sizes, int n_in,
                              void* d_out, int out_size, void* d_ws, size_t ws_size,
                              hipStream_t stream) {
  const float* x      = (const float*)d_in[0];
  const int*   ei     = (const int*)d_in[1];
  const int*   attr   = (const int*)d_in[2];
  const float* Wg     = (const float*)d_in[3];
  const float* a_src  = (const float*)d_in[4];
  const float* a_dst  = (const float*)d_in[5];
  const float* b_gat  = (const float*)d_in[6];
  const float* etw    = (const float*)d_in[7];
  const float* W_fuse = (const float*)d_in[8];
  const float* b_fuse = (const float*)d_in[9];
  const float* gamma  = (const float*)d_in[10];
  const float* beta   = (const float*)d_in[11];

  const int N = in_sizes[0] / DD;
  const int E = in_sizes[2];
  const int* src = ei;
  const int* dst = ei + E;
  const int M = TT * N;

  char* ws = (char*)d_ws;
  size_t off = 0;
  auto alloc = [&](size_t bytes) {
    void* p = ws + off;
    off += (bytes + 255) & ~(size_t)255;
    return p;
  };
  unsigned short* AGG   = (unsigned short*)alloc((size_t)N * KAGG * 2);      // 204.8MB
  unsigned short* xb    = (unsigned short*)alloc((size_t)N * DD * 2);        // 12.8MB
  unsigned short* Gfrag = (unsigned short*)alloc((size_t)512 * 512 * 2);     // 512KB
  unsigned short* Pall  = (unsigned short*)alloc((size_t)32 * DD * 2);       // 8KB
  float* cbias          = (float*)alloc(128 * sizeof(float));
  float* as_            = (float*)alloc((size_t)TT * N * 4 * sizeof(float)); // 3.2MB
  float* ad_            = (float*)alloc((size_t)TT * N * 4 * sizeof(float));
  int* deg              = (int*)alloc((size_t)(M + 1) * sizeof(int));        // +1 = gcur
  int* rowptr           = (int*)alloc((size_t)M * sizeof(int));
  int* cursor           = (int*)alloc((size_t)M * sizeof(int));
  int* slist            = (int*)alloc((size_t)E * sizeof(int));              // 1.3MB

  hipMemsetAsync(deg, 0, (size_t)(M + 1) * sizeof(int), stream);

  int total4x = N * DD / 4;
  int nconv = (total4x + 255) / 256;
  int nhist = (E + 255) / 256;
  prologue_kernel<<<nconv + 17 + nhist, 256, 0, stream>>>(
      x, xb, total4x, Wg, a_src, a_dst, W_fuse, b_gat, etw, b_fuse,
      Pall, cbias, dst, attr, deg, E, N);

  gprep_kernel<<<256, 256, 0, stream>>>(Wg, W_fuse, etw, Gfrag);

  scanfused_kernel<<<(M + 1023) / 1024, 1024, 0, stream>>>(deg, rowptr, cursor,
                                                           deg + M, M);

  int nalpha = (N + 127) / 128;
  scatter_alpha_kernel<<<nhist + nalpha, 256, 0, stream>>>(
      src, dst, attr, cursor, slist, xb, Pall, as_, ad_, E, N);

  dim3 ggrid((N + 15) / 16, TT);
  gather_kernel<<<ggrid, 256, 0, stream>>>(slist, rowptr, deg, as_, ad_, xb, AGG, N);

  gemmln_kernel<<<(N + 63) / 64, 256, 0, stream>>>(AGG, Gfrag, cbias, gamma, beta,
                                                   (float*)d_out, N);
}